// Round 1
// baseline (1137.524 us; speedup 1.0000x reference)
//
#include <hip/hip_runtime.h>

// K1: precompute per-step coefficients and transpose to [t][b] float4 layout.
// w4[t*B+b] = (L1, a3, a4, signbits) where
//   L1 = fl(m_lo*x + m_lo*c_lo), a3 = m_lo... (see below), bits = sign(m_lo) | sign(m_up)<<1
__global__ __launch_bounds__(256) void prep_kernel(
    const float* __restrict__ x, const float4* __restrict__ lstm,
    float4* __restrict__ w4, int B, int T) {
#pragma clang fp contract(off)
  __shared__ float4 tile[32][33];  // [b-within][t-within], padded
  int t0 = blockIdx.x * 32;
  int b0 = blockIdx.y * 32;
  int tid = threadIdx.x;
  int c = tid & 31;   // t offset on read, b offset on write
  int r0 = tid >> 5;  // 0..7
#pragma unroll
  for (int k = 0; k < 4; ++k) {
    int r = r0 + k * 8;  // b offset
    int b = b0 + r, t = t0 + c;
    float xt = x[(size_t)b * T + t];
    float4 wv = lstm[(size_t)b * T + t];  // (m_lo, m_up, c_lo, c_up)
    float a1 = wv.x * xt;
    float a2 = wv.x * wv.z;
    float L1 = a1 + a2;          // exact for both num1 and the f1-output term
    float a3 = wv.y * xt;
    float a4 = wv.y * wv.w;
    unsigned bits = (__float_as_uint(wv.x) >> 31) |
                    ((__float_as_uint(wv.y) >> 31) << 1);
    tile[r][c] = make_float4(L1, a3, a4, __uint_as_float(bits));
  }
  __syncthreads();
#pragma unroll
  for (int k = 0; k < 4; ++k) {
    int r = r0 + k * 8;  // t offset
    w4[(size_t)(t0 + r) * B + (b0 + c)] = tile[c][r];
  }
}

// K2: the sequential scan. One thread per row b; lanes of a wave cover 64
// consecutive b -> every load/store is coalesced in the [t][b] layout.
// PF-deep register ring buffer prefetches t+PF while computing t.
#define PF 16
__global__ __launch_bounds__(64) void scan_kernel(
    const float4* __restrict__ w4, const float* __restrict__ p0,
    float* __restrict__ outT, int B, int T) {
#pragma clang fp contract(off)
  int gid = blockIdx.x * 64 + threadIdx.x;  // = b
  float p = p0[gid];
  float4 buf[PF];
#pragma unroll
  for (int i = 0; i < PF; ++i) buf[i] = w4[(size_t)i * B + gid];
  for (int tb = 0; tb < T; tb += PF) {
#pragma unroll
    for (int i = 0; i < PF; ++i) {
      float4 w = buf[i];
      int tn = tb + i + PF;
      if (tn < T) buf[i] = w4[(size_t)tn * B + gid];
      unsigned ub = __float_as_uint(w.w);
      unsigned m1 = ub << 31;          // sign(m_lo) in bit 31
      unsigned m2 = (ub & 2u) << 30;   // sign(m_up) in bit 31
      // f1 = h((L1 - p)/m_lo): sign of quotient == sign(n1) xor sign(m_lo)
      float n1 = w.x - p;
      float n1s = __uint_as_float(__float_as_uint(n1) ^ m1);
      bool c1 = !(n1s > 0.0f);  // f1 == 1
      // f2 = h(((p - a3) - a4)/m_up), numpy left-assoc order preserved
      float n2 = (p - w.y) - w.z;
      float n2s = __uint_as_float(__float_as_uint(n2) ^ m2);
      bool c2 = !(n2s > 0.0f);  // f2 == 1
      // out = a1*f1 + a2*f1 + a3*f2 + a4*f2 + p*(1-f1)*(1-f2), left-assoc:
      // f1 term collapses exactly to L1 (fl(a1+a2)); +0 adds are exact.
      float acc = c1 ? w.x : 0.0f;
      acc = acc + (c2 ? w.y : 0.0f);
      acc = acc + (c2 ? w.z : 0.0f);
      acc = acc + ((c1 || c2) ? 0.0f : p);
      p = acc;
      outT[(size_t)(tb + i) * B + gid] = acc;
    }
  }
}

// K3: transpose out_T[t][b] -> out[b][t], tiled through LDS, both sides coalesced.
__global__ __launch_bounds__(256) void tr_kernel(
    const float* __restrict__ outT, float* __restrict__ out, int B, int T) {
  __shared__ float tile[32][33];
  int t0 = blockIdx.x * 32;
  int b0 = blockIdx.y * 32;
  int tid = threadIdx.x;
  int c = tid & 31;
  int r0 = tid >> 5;
#pragma unroll
  for (int k = 0; k < 4; ++k) {
    int r = r0 + k * 8;  // t offset
    tile[r][c] = outT[(size_t)(t0 + r) * B + (b0 + c)];
  }
  __syncthreads();
#pragma unroll
  for (int k = 0; k < 4; ++k) {
    int r = r0 + k * 8;  // b offset
    out[(size_t)(b0 + r) * T + (t0 + c)] = tile[c][r];
  }
}

extern "C" void kernel_launch(void* const* d_in, const int* in_sizes, int n_in,
                              void* d_out, int out_size, void* d_ws, size_t ws_size,
                              hipStream_t stream) {
  const float* x = (const float*)d_in[0];        // (B, T, 1) fp32
  const float* op = (const float*)d_in[1];       // (B, 1, 1) fp32
  const float4* lstm = (const float4*)d_in[2];   // (B, T, 4) fp32
  int B = in_sizes[1];            // 4096
  int T = in_sizes[0] / B;        // 2048
  float4* w4 = (float4*)d_ws;                                   // B*T*16 bytes
  float* outT = (float*)((char*)d_ws + (size_t)B * T * sizeof(float4));  // B*T*4
  dim3 g1(T / 32, B / 32);
  hipLaunchKernelGGL(prep_kernel, g1, dim3(256), 0, stream, x, lstm, w4, B, T);
  hipLaunchKernelGGL(scan_kernel, dim3(B / 64), dim3(64), 0, stream, w4, op, outT,
                     B, T);
  hipLaunchKernelGGL(tr_kernel, g1, dim3(256), 0, stream, outT, (float*)d_out, B, T);
}

// Round 2
// 383.295 us; speedup vs baseline: 2.9677x; 2.9677x over previous
//
#include <hip/hip_runtime.h>

// K1: precompute per-step coefficients and transpose to [t][b] float4 layout.
// w4[t*B+b] = (L1, a3, a4, signbits):
//   L1 = fl(fl(m_lo*x) + fl(m_lo*c_lo))  (exact for num1 and the f1 output term)
//   a3 = fl(m_up*x), a4 = fl(m_up*c_up)
//   bits = sign(m_lo) | sign(m_up)<<1
__global__ __launch_bounds__(256) void prep_kernel(
    const float* __restrict__ x, const float4* __restrict__ lstm,
    float4* __restrict__ w4, int B, int T) {
#pragma clang fp contract(off)
  __shared__ float4 tile[32][33];  // [b-within][t-within], padded
  int t0 = blockIdx.x * 32;
  int b0 = blockIdx.y * 32;
  int tid = threadIdx.x;
  int c = tid & 31;
  int r0 = tid >> 5;
#pragma unroll
  for (int k = 0; k < 4; ++k) {
    int r = r0 + k * 8;
    int b = b0 + r, t = t0 + c;
    float xt = x[(size_t)b * T + t];
    float4 wv = lstm[(size_t)b * T + t];  // (m_lo, m_up, c_lo, c_up)
    float a1 = wv.x * xt;
    float a2 = wv.x * wv.z;
    float L1 = a1 + a2;
    float a3 = wv.y * xt;
    float a4 = wv.y * wv.w;
    unsigned bits = (__float_as_uint(wv.x) >> 31) |
                    ((__float_as_uint(wv.y) >> 31) << 1);
    tile[r][c] = make_float4(L1, a3, a4, __uint_as_float(bits));
  }
  __syncthreads();
#pragma unroll
  for (int k = 0; k < 4; ++k) {
    int r = r0 + k * 8;
    w4[(size_t)(t0 + r) * B + (b0 + c)] = tile[c][r];
  }
}

// K2: sequential scan, one thread per row b, lanes = 64 consecutive b.
// PF named float4 registers form the prefetch ring (cannot be demoted).
// Output transpose fused: 64x64 tile staged in LDS (padded, conflict-free),
// stored to d_out[b][t] coalesced.
#define PF 16

#define DECLQ(i) float4 q##i = w4[(size_t)(i) * Bs + gid];

#define STEP(i)                                                              \
  {                                                                          \
    float4 w = q##i;                                                         \
    q##i = *wf;   /* prefetch t+PF; tail reads spill <=1MB past w4 in ws */  \
    wf += Bs;                                                                \
    unsigned ub = __float_as_uint(w.w);                                      \
    unsigned s1 = ub << 31;                                                  \
    unsigned s2 = (ub & 2u) << 30;                                           \
    float n1 = __uint_as_float(__float_as_uint(w.x - p) ^ s1);               \
    float n2 = __uint_as_float(__float_as_uint((p - w.y) - w.z) ^ s2);       \
    bool c1 = !(n1 > 0.0f);                                                  \
    bool c2 = !(n2 > 0.0f);                                                  \
    float acc = c1 ? w.x : 0.0f;                                             \
    acc = acc + (c2 ? w.y : 0.0f);                                           \
    acc = acc + (c2 ? w.z : 0.0f);                                           \
    acc = acc + ((c1 || c2) ? 0.0f : p);                                     \
    p = acc;                                                                 \
    stg[(unsigned)((t + (i)) & 63) * 65u + lane] = p;                        \
  }

__global__ __launch_bounds__(64) void scan_kernel(
    const float4* __restrict__ w4, const float* __restrict__ p0,
    float* __restrict__ out, int B, int T) {
#pragma clang fp contract(off)
  __shared__ float stg[64 * 65];  // [local step s][lane], padded: both sides 2-way (free)
  const int lane = threadIdx.x;
  const int b0 = blockIdx.x * 64;
  const int gid = b0 + lane;
  const size_t Bs = (size_t)B;
  float p = p0[gid];
  DECLQ(0)  DECLQ(1)  DECLQ(2)  DECLQ(3)
  DECLQ(4)  DECLQ(5)  DECLQ(6)  DECLQ(7)
  DECLQ(8)  DECLQ(9)  DECLQ(10) DECLQ(11)
  DECLQ(12) DECLQ(13) DECLQ(14) DECLQ(15)
  const float4* wf = w4 + (size_t)PF * Bs + gid;
  for (int t = 0; t < T; t += 16) {
    STEP(0)  STEP(1)  STEP(2)  STEP(3)
    STEP(4)  STEP(5)  STEP(6)  STEP(7)
    STEP(8)  STEP(9)  STEP(10) STEP(11)
    STEP(12) STEP(13) STEP(14) STEP(15)
    if ((t & 63) == 48) {  // slots 0..63 of this 64-step window are complete
      int t0 = t - 48;
      __syncthreads();  // 1 wave/block: ~free; forces LDS writes visible
#pragma unroll 8
      for (int j = 0; j < 64; ++j) {
        // row b0+j, t-range t0..t0+63: lane l stores element t0+l.
        out[(size_t)(b0 + j) * T + (t0 + lane)] = stg[(unsigned)lane * 65u + j];
      }
      __syncthreads();
    }
  }
}

extern "C" void kernel_launch(void* const* d_in, const int* in_sizes, int n_in,
                              void* d_out, int out_size, void* d_ws, size_t ws_size,
                              hipStream_t stream) {
  const float* x = (const float*)d_in[0];        // (B, T, 1) fp32
  const float* op = (const float*)d_in[1];       // (B, 1, 1) fp32
  const float4* lstm = (const float4*)d_in[2];   // (B, T, 4) fp32
  int B = in_sizes[1];      // 4096
  int T = in_sizes[0] / B;  // 2048
  // ws layout: w4 = B*T*16 B = 128 MB; scan prefetch over-reads <= PF*B*16 B
  // = 1 MB past its end (round-1 run already used 160 MB of ws, so it exists).
  float4* w4 = (float4*)d_ws;
  dim3 g1(T / 32, B / 32);
  hipLaunchKernelGGL(prep_kernel, g1, dim3(256), 0, stream, x, lstm, w4, B, T);
  hipLaunchKernelGGL(scan_kernel, dim3(B / 64), dim3(64), 0, stream, w4, op,
                     (float*)d_out, B, T);
}

// Round 3
// 293.961 us; speedup vs baseline: 3.8696x; 1.3039x over previous
//
#include <hip/hip_runtime.h>

// Fused single-kernel backlash scan.
// Grid: B/R blocks x 64 threads (1 wave). Each block owns R=16 rows.
// Per chunk of C=64 steps:
//   - all 64 lanes issue global loads for chunk c+1 (lstm: 16x b128, x: 4x b128)
//   - 16 leader lanes scan chunk c from LDS coefficient tile (double-buffered)
//   - all lanes flush chunk c outputs via padded-LDS transpose (coalesced stores)
//   - all lanes stage chunk c+1: x -> LDS, then per-element coefficients
//       L1 = fl(fl(m_lo*x)+fl(m_lo*c_lo)), a3 = fl(m_up*x), a4 = fl(m_up*c_up),
//       bits = sign(m_lo) | sign(m_up)<<1   (bit-exact vs numpy, as in round 2)
// Single wave per block => no __syncthreads anywhere => no vmcnt(0) drains.

#define R 16    // rows per block
#define C 64    // steps per chunk
#define PADF 17 // padded stride (floats or float4s) => all LDS patterns <=2-way

__global__ __launch_bounds__(64) void fused_scan(
    const float* __restrict__ x, const float* __restrict__ p0,
    const float4* __restrict__ lstm4, float* __restrict__ out,
    int B, int T) {
#pragma clang fp contract(off)
  __shared__ float4 wt[2][C * PADF];  // coefficient tiles [step][row], padded
  __shared__ float xt[C * PADF];      // x staging [step][row], padded
  __shared__ float ostg[C * PADF];    // output staging [step][row], padded

  const int lane = threadIdx.x;
  const int b0 = blockIdx.x * R;
  const int half = lane >> 5;   // 0/1
  const int tl = lane & 31;     // 0..31
  const int nchunk = T / C;
  const float4* x4 = reinterpret_cast<const float4*>(x);

  float4 lreg[16];
  float4 xreg[4];

  auto issue_loads = [&](int t0n) {
#pragma unroll
    for (int k = 0; k < 16; ++k) {
      int r = 2 * (k & 7) + half;         // row 0..15
      int toff = (k >> 3) * 32 + tl;      // t 0..63
      lreg[k] = lstm4[(size_t)(b0 + r) * T + t0n + toff];
    }
#pragma unroll
    for (int m = 0; m < 4; ++m) {
      int r = 4 * m + (lane >> 4);        // row 0..15
      int toff = (lane & 15) * 4;         // t 0..60 step 4
      xreg[m] = x4[((size_t)(b0 + r) * T + t0n + toff) >> 2];
    }
  };

  auto stage = [&](int buf) {
#pragma clang fp contract(off)
    // x -> LDS [step][row]
#pragma unroll
    for (int m = 0; m < 4; ++m) {
      int r = 4 * m + (lane >> 4);
      int toff = (lane & 15) * 4;
      xt[(toff + 0) * PADF + r] = xreg[m].x;
      xt[(toff + 1) * PADF + r] = xreg[m].y;
      xt[(toff + 2) * PADF + r] = xreg[m].z;
      xt[(toff + 3) * PADF + r] = xreg[m].w;
    }
    // lstm + x -> coefficient tile (in-wave DS ordering makes xt visible)
#pragma unroll
    for (int k = 0; k < 16; ++k) {
      int r = 2 * (k & 7) + half;
      int s = (k >> 3) * 32 + tl;
      float xv = xt[s * PADF + r];
      float4 wv = lreg[k];  // (m_lo, m_up, c_lo, c_up)
      float a1 = wv.x * xv;
      float a2 = wv.x * wv.z;
      float L1 = a1 + a2;
      float a3 = wv.y * xv;
      float a4 = wv.y * wv.w;
      unsigned bits = (__float_as_uint(wv.x) >> 31) |
                      ((__float_as_uint(wv.y) >> 31) << 1);
      wt[buf][s * PADF + r] = make_float4(L1, a3, a4, __uint_as_float(bits));
    }
  };

  float p = (lane < R) ? p0[b0 + lane] : 0.0f;

  issue_loads(0);
  stage(0);
  int cur = 0;

  for (int c = 0; c < nchunk; ++c) {
    const int t0 = c * C;
    const int t0n = (c + 1 < nchunk) ? t0 + C : 0;  // tail: harmless reload of chunk 0
    issue_loads(t0n);

    // ---- scan chunk c (leader lanes; coefficients from LDS) ----
    if (lane < R) {
      const int j = lane;
#pragma unroll
      for (int s = 0; s < C; ++s) {
        float4 w = wt[cur][s * PADF + j];
        unsigned ub = __float_as_uint(w.w);
        unsigned s1 = ub << 31;          // sign(m_lo) -> bit 31
        unsigned s2 = (ub & 2u) << 30;   // sign(m_up) -> bit 31
        float n1 = __uint_as_float(__float_as_uint(w.x - p) ^ s1);
        float n2 = __uint_as_float(__float_as_uint((p - w.y) - w.z) ^ s2);
        bool c1 = !(n1 > 0.0f);
        bool c2 = !(n2 > 0.0f);
        float acc = c1 ? w.x : 0.0f;
        acc = acc + (c2 ? w.y : 0.0f);
        acc = acc + (c2 ? w.z : 0.0f);
        acc = acc + ((c1 || c2) ? 0.0f : p);
        p = acc;
        ostg[s * PADF + j] = p;
      }
    }

    // ---- flush chunk c: LDS transpose -> coalesced float4 stores ----
#pragma unroll
    for (int k2 = 0; k2 < 4; ++k2) {
      int jo = 4 * k2 + (lane >> 4);
      int tq = (lane & 15) * 4;
      float4 v;
      v.x = ostg[(tq + 0) * PADF + jo];
      v.y = ostg[(tq + 1) * PADF + jo];
      v.z = ostg[(tq + 2) * PADF + jo];
      v.w = ostg[(tq + 3) * PADF + jo];
      reinterpret_cast<float4*>(out)[((size_t)(b0 + jo) * T + t0 + tq) >> 2] = v;
    }

    // ---- stage chunk c+1 into the other buffer ----
    stage(cur ^ 1);
    cur ^= 1;
  }
}

extern "C" void kernel_launch(void* const* d_in, const int* in_sizes, int n_in,
                              void* d_out, int out_size, void* d_ws, size_t ws_size,
                              hipStream_t stream) {
  const float* x = (const float*)d_in[0];        // (B, T, 1) fp32
  const float* op = (const float*)d_in[1];       // (B, 1, 1) fp32
  const float4* lstm = (const float4*)d_in[2];   // (B, T, 4) fp32
  int B = in_sizes[1];      // 4096
  int T = in_sizes[0] / B;  // 2048
  hipLaunchKernelGGL(fused_scan, dim3(B / R), dim3(64), 0, stream,
                     x, op, lstm, (float*)d_out, B, T);
}

// Round 4
// 260.388 us; speedup vs baseline: 4.3686x; 1.1289x over previous
//
#include <hip/hip_runtime.h>

// Producer/consumer fused backlash scan.
// Grid: 256 blocks x 192 threads (3 waves). Block owns R=16 rows.
// Wave 0 lanes 0..15: consumer (the recurrence). Waves 1-2 (128 lanes): producers.
// Chunks of C=32 steps, double-buffered coefficient tiles + output staging.
// Barrier = s_waitcnt lgkmcnt(0) + s_barrier: LDS visible, global loads stay in flight.
//
// Per (row,step) the producers precompute 8 words (exact, contract off):
//   s1m = signbit(m_lo)                    (mask 0x80000000 or 0)
//   L1  = fl(fl(m_lo*x) + fl(m_lo*c_lo));  L1f = L1 ^ s1m
//   f2m = signbit(m_up) ^ 0x80000000
//   a3  = fl(m_up*x);  a4 = fl(m_up*c_up); a3f = a3^f2m; a4f = a4^f2m
//   V01 = fl(a3+a4);   V11 = fl(fl(L1+a3)+a4)
// Consumer step (p-chain ~16 cyc):
//   c1 = (p^s1m) >= L1f        == h(num1/m_lo)   (exact incl. zeros/boundaries)
//   c2 = ((p^f2m) - a3f) >= a4f == h(num2/m_up)  (neg of exact sub is exact)
//   p  = c2 ? (c1 ? V11 : V01) : (c1 ? L1 : p)

#define C 32
#define NCH 64  // T / C

#define WG_BARRIER() asm volatile("s_waitcnt lgkmcnt(0)\ns_barrier" ::: "memory")

__global__ __launch_bounds__(192) void pc_scan(
    const float* __restrict__ x, const float* __restrict__ p0,
    const float4* __restrict__ lstm4, float* __restrict__ out,
    int B, int T) {
#pragma clang fp contract(off)
  __shared__ float4 tileA[2][C * 17];  // (s1m, L1f, f2m, a3f), row-pad 17
  __shared__ float4 tileB[2][C * 17];  // (a4f, V11, V01, L1)
  __shared__ float ostg[2][16 * 36];   // [row][step], pad 36

  const int tid = threadIdx.x;
  const int b0 = blockIdx.x * 16;
  const float4* x4 = reinterpret_cast<const float4*>(x);
  float4* out4 = reinterpret_cast<float4*>(out);

  // producer element mapping: q in [0,128): row pj, t-quad pk (4 steps each)
  const int q = tid - 64;
  const int pj = (q >> 3) & 15;
  const int pk = q & 7;

  float4 X0, X1, L00, L01, L02, L03, L10, L11, L12, L13;

#define ISSUE(S, CH)                                              \
  if (tid >= 64) {                                                \
    size_t base = (size_t)(b0 + pj) * T + (CH) * C + 4 * pk;      \
    X##S = x4[base >> 2];                                         \
    L##S##0 = lstm4[base + 0];                                    \
    L##S##1 = lstm4[base + 1];                                    \
    L##S##2 = lstm4[base + 2];                                    \
    L##S##3 = lstm4[base + 3];                                    \
  }

#define STAGE_ELT(S, I, XC, BUF)                                            \
  {                                                                         \
    float4 wv = L##S##I;                                                    \
    float xv = XC;                                                          \
    float a1 = wv.x * xv, a2 = wv.x * wv.z;                                 \
    float L1v = a1 + a2;                                                    \
    unsigned s1m = __float_as_uint(wv.x) & 0x80000000u;                     \
    float L1f = __uint_as_float(__float_as_uint(L1v) ^ s1m);                \
    float a3 = wv.y * xv, a4 = wv.y * wv.w;                                 \
    unsigned f2m = (__float_as_uint(wv.y) & 0x80000000u) ^ 0x80000000u;     \
    float a3f = __uint_as_float(__float_as_uint(a3) ^ f2m);                 \
    float a4f = __uint_as_float(__float_as_uint(a4) ^ f2m);                 \
    float V01 = a3 + a4;                                                    \
    float V11 = (L1v + a3) + a4;                                            \
    int s = 4 * pk + I;                                                     \
    tileA[BUF][s * 17 + pj] =                                               \
        make_float4(__uint_as_float(s1m), L1f, __uint_as_float(f2m), a3f);  \
    tileB[BUF][s * 17 + pj] = make_float4(a4f, V11, V01, L1v);              \
  }

#define STAGE(S, BUF)                    \
  if (tid >= 64) {                       \
    STAGE_ELT(S, 0, X##S.x, BUF)         \
    STAGE_ELT(S, 1, X##S.y, BUF)         \
    STAGE_ELT(S, 2, X##S.z, BUF)         \
    STAGE_ELT(S, 3, X##S.w, BUF)         \
  }

#define FLUSH(CP, BP)                                                       \
  if (tid >= 64) {                                                          \
    float4 v = *(const float4*)&ostg[BP][pj * 36 + 4 * pk];                 \
    out4[((size_t)(b0 + pj) * T + (CP) * C + 4 * pk) >> 2] = v;             \
  }

#define SCAN(BUF)                                                           \
  if (tid < 16) {                                                           \
    _Pragma("unroll") for (int s = 0; s < C; ++s) {                         \
      float4 A = tileA[BUF][s * 17 + tid];                                  \
      float4 Bv = tileB[BUF][s * 17 + tid];                                 \
      unsigned pu = __float_as_uint(p);                                     \
      float pf = __uint_as_float(pu ^ __float_as_uint(A.x));                \
      bool c1 = pf >= A.y;                                                  \
      float pp = __uint_as_float(pu ^ __float_as_uint(A.z));                \
      float qv = pp - A.w;                                                  \
      bool c2 = qv >= Bv.x;                                                 \
      float i1 = c1 ? Bv.y : Bv.z;                                          \
      float i2 = c1 ? Bv.w : p;                                             \
      p = c2 ? i1 : i2;                                                     \
      ostg[BUF][tid * 36 + s] = p;                                          \
    }                                                                       \
  }

  float p = (tid < 16) ? p0[b0 + tid] : 0.0f;

  // prologue: stage chunk 0 into buf0, issue chunk 1 into set 1
  ISSUE(0, 0)
  STAGE(0, 0)
  ISSUE(1, 1)
  WG_BARRIER();

  for (int c = 0; c < NCH; c += 2) {
    // even iter: consumer scans chunk c (buf0); producers: issue c+2,
    // stage c+1 -> buf1, flush chunk c-1 (ostg1)
    if (c + 2 < NCH) ISSUE(0, c + 2)
    STAGE(1, 1)
    if (c >= 1) FLUSH(c - 1, 1)
    SCAN(0)
    WG_BARRIER();

    // odd iter: consumer scans chunk c+1 (buf1); producers: issue c+3,
    // stage c+2 -> buf0, flush chunk c (ostg0)
    if (c + 3 < NCH) ISSUE(1, c + 3)
    if (c + 2 < NCH) STAGE(0, 0)
    FLUSH(c, 0)
    SCAN(1)
    WG_BARRIER();
  }
  // chunk 63 outputs (written to ostg1 in the last odd iter)
  FLUSH(NCH - 1, 1)
}

extern "C" void kernel_launch(void* const* d_in, const int* in_sizes, int n_in,
                              void* d_out, int out_size, void* d_ws, size_t ws_size,
                              hipStream_t stream) {
  const float* x = (const float*)d_in[0];        // (B, T, 1) fp32
  const float* op = (const float*)d_in[1];       // (B, 1, 1) fp32
  const float4* lstm = (const float4*)d_in[2];   // (B, T, 4) fp32
  int B = in_sizes[1];      // 4096
  int T = in_sizes[0] / B;  // 2048
  hipLaunchKernelGGL(pc_scan, dim3(B / 16), dim3(192), 0, stream,
                     x, op, lstm, (float*)d_out, B, T);
}

// Round 5
// 237.360 us; speedup vs baseline: 4.7924x; 1.0970x over previous
//
#include <hip/hip_runtime.h>

// Producer/consumer fused backlash scan, R5.
// Grid: 256 blocks x 192 threads (3 waves). Block owns 16 rows.
// Wave 0 lanes 0..15: consumer (recurrence). Waves 1-2: producers.
// Chunks of C=64 steps, double-buffered tiles; barrier = lgkmcnt(0)+s_barrier
// so global loads stay in flight across barriers.
//
// LDS layouts (all conflict-free per 16-lane phase):
//   tileA/B[buf][row][step], row stride TS=65 float4 (word stride 260 % 32 == 4)
//   xt / ostg [row][step], row stride XS=68 floats
// Producer lane q=tid-64: pj=(q>>3)&15 (row), pk=q&7; handles steps s=pk+8I.
// Step math verbatim from round 4 (bit-exact vs numpy):
//   c1 = (p^s1m) >= L1f ; c2 = ((p^f2m) - a3f) >= a4f
//   p  = c2 ? (c1 ? V11 : V01) : (c1 ? L1 : p)

#define C 64
#define NCH 32  // T / C
#define TS 65   // tile row stride (float4)
#define XS 68   // xt/ostg row stride (floats)

#define WG_BARRIER() asm volatile("s_waitcnt lgkmcnt(0)\ns_barrier" ::: "memory")

__global__ __launch_bounds__(192) void pc_scan(
    const float* __restrict__ x, const float* __restrict__ p0,
    const float4* __restrict__ lstm4, float* __restrict__ out,
    int B, int T) {
#pragma clang fp contract(off)
  __shared__ float4 tileA[2][16 * TS];  // (s1m, L1f, f2m, a3f)
  __shared__ float4 tileB[2][16 * TS];  // (a4f, V11, V01, L1)
  __shared__ float xt[16 * XS];         // x exchange [row][step]
  __shared__ float ostg[2][16 * XS];    // outputs [row][step]

  const int tid = threadIdx.x;
  const int b0 = blockIdx.x * 16;
  const float4* x4 = reinterpret_cast<const float4*>(x);
  float4* out4 = reinterpret_cast<float4*>(out);

  const int q = tid - 64;
  const int pj = (q >> 3) & 15;  // row
  const int pk = q & 7;          // step phase

  float4 L00, L01, L02, L03, L04, L05, L06, L07;
  float4 L10, L11, L12, L13, L14, L15, L16, L17;
  float4 X00, X01, X10, X11;

#define ISSUE(S, CH)                                                    \
  if (tid >= 64) {                                                      \
    size_t rb = (size_t)(b0 + pj) * T + (size_t)(CH) * C;               \
    const float4* lp = lstm4 + rb + pk;                                 \
    L##S##0 = lp[0];  L##S##1 = lp[8];  L##S##2 = lp[16];               \
    L##S##3 = lp[24]; L##S##4 = lp[32]; L##S##5 = lp[40];               \
    L##S##6 = lp[48]; L##S##7 = lp[56];                                 \
    X##S##0 = x4[(rb >> 2) + 2 * pk];                                   \
    X##S##1 = x4[(rb >> 2) + 2 * pk + 1];                               \
  }

#define STAGE_ELT(LV, SS, BUF)                                          \
  {                                                                     \
    float4 wv = LV; /* (m_lo, m_up, c_lo, c_up) */                      \
    float xv = xt[pj * XS + (SS)];                                      \
    float a1 = wv.x * xv, a2 = wv.x * wv.z;                             \
    float L1v = a1 + a2;                                                \
    unsigned s1m = __float_as_uint(wv.x) & 0x80000000u;                 \
    float L1f = __uint_as_float(__float_as_uint(L1v) ^ s1m);            \
    float a3 = wv.y * xv, a4 = wv.y * wv.w;                             \
    unsigned f2m = (__float_as_uint(wv.y) & 0x80000000u) ^ 0x80000000u; \
    float a3f = __uint_as_float(__float_as_uint(a3) ^ f2m);             \
    float a4f = __uint_as_float(__float_as_uint(a4) ^ f2m);             \
    float V01 = a3 + a4;                                                \
    float V11 = (L1v + a3) + a4;                                        \
    tileA[BUF][pj * TS + (SS)] =                                        \
        make_float4(__uint_as_float(s1m), L1f, __uint_as_float(f2m), a3f); \
    tileB[BUF][pj * TS + (SS)] = make_float4(a4f, V11, V01, L1v);       \
  }

#define STAGE(S, BUF)                                                   \
  if (tid >= 64) {                                                      \
    *(float4*)&xt[pj * XS + 8 * pk] = X##S##0;                          \
    *(float4*)&xt[pj * XS + 8 * pk + 4] = X##S##1;                      \
    STAGE_ELT(L##S##0, pk,      BUF)                                    \
    STAGE_ELT(L##S##1, pk + 8,  BUF)                                    \
    STAGE_ELT(L##S##2, pk + 16, BUF)                                    \
    STAGE_ELT(L##S##3, pk + 24, BUF)                                    \
    STAGE_ELT(L##S##4, pk + 32, BUF)                                    \
    STAGE_ELT(L##S##5, pk + 40, BUF)                                    \
    STAGE_ELT(L##S##6, pk + 48, BUF)                                    \
    STAGE_ELT(L##S##7, pk + 56, BUF)                                    \
  }

#define FLUSH(CP, OB)                                                   \
  if (tid >= 64) {                                                      \
    float4 v0 = *(const float4*)&ostg[OB][pj * XS + 8 * pk];            \
    float4 v1 = *(const float4*)&ostg[OB][pj * XS + 8 * pk + 4];        \
    size_t ob = ((size_t)(b0 + pj) * T + (size_t)(CP) * C) >> 2;        \
    out4[ob + 2 * pk] = v0;                                             \
    out4[ob + 2 * pk + 1] = v1;                                         \
  }

#define SCAN(BUF, OB)                                                   \
  if (tid < 16) {                                                       \
    _Pragma("unroll") for (int s = 0; s < C; ++s) {                     \
      float4 A = tileA[BUF][tid * TS + s];                              \
      float4 Bv = tileB[BUF][tid * TS + s];                             \
      unsigned pu = __float_as_uint(p);                                 \
      float pf = __uint_as_float(pu ^ __float_as_uint(A.x));            \
      bool c1 = pf >= A.y;                                              \
      float pp = __uint_as_float(pu ^ __float_as_uint(A.z));            \
      float qv = pp - A.w;                                              \
      bool c2 = qv >= Bv.x;                                             \
      float i1 = c1 ? Bv.y : Bv.z;                                      \
      float i2 = c1 ? Bv.w : p;                                         \
      p = c2 ? i1 : i2;                                                 \
      ostg[OB][tid * XS + s] = p;                                       \
    }                                                                   \
  }

  float p = (tid < 16) ? p0[b0 + tid] : 0.0f;

  // prologue: chunk0 -> buf0; chunk1 loads in flight (set1)
  ISSUE(0, 0)
  STAGE(0, 0)
  ISSUE(1, 1)
  WG_BARRIER();

  for (int c = 0; c < NCH; c += 2) {
    // even phase: scan chunk c (buf0); issue c+2 (set0); stage c+1 (set1->buf1);
    // flush chunk c-1 (ostg1)
    if (c + 2 < NCH) ISSUE(0, c + 2)
    STAGE(1, 1)
    if (c >= 1) FLUSH(c - 1, 1)
    SCAN(0, 0)
    WG_BARRIER();

    // odd phase: scan chunk c+1 (buf1); issue c+3 (set1); stage c+2 (set0->buf0);
    // flush chunk c (ostg0)
    if (c + 3 < NCH) ISSUE(1, c + 3)
    if (c + 2 < NCH) STAGE(0, 0)
    FLUSH(c, 0)
    SCAN(1, 1)
    WG_BARRIER();
  }
  FLUSH(NCH - 1, 1)  // last (odd) chunk's outputs
}

extern "C" void kernel_launch(void* const* d_in, const int* in_sizes, int n_in,
                              void* d_out, int out_size, void* d_ws, size_t ws_size,
                              hipStream_t stream) {
  const float* x = (const float*)d_in[0];        // (B, T, 1) fp32
  const float* op = (const float*)d_in[1];       // (B, 1, 1) fp32
  const float4* lstm = (const float4*)d_in[2];   // (B, T, 4) fp32
  int B = in_sizes[1];      // 4096
  int T = in_sizes[0] / B;  // 2048
  hipLaunchKernelGGL(pc_scan, dim3(B / 16), dim3(192), 0, stream,
                     x, op, lstm, (float*)d_out, B, T);
}

// Round 6
// 237.163 us; speedup vs baseline: 4.7964x; 1.0008x over previous
//
#include <hip/hip_runtime.h>

// Producer/consumer fused backlash scan, R6.
// Grid: 512 blocks x 192 threads (3 waves), 2 blocks/CU. Block owns 8 rows.
// Wave 0 lanes 0..7: consumer (recurrence, 8-deep LDS->reg ring).
// Waves 1-2 (128 lanes): producers; lane q: pj=q>>4 (row), pk=q&15.
// Chunks of C=64 steps, double-buffered tiles; barrier = lgkmcnt(0)+s_barrier
// so global loads stay in flight across barriers.
//
// LDS (all patterns verified conflict-free / <=2-way per 16-lane phase):
//   tileA/B[buf][row][step], row stride TS=65 float4 (word stride 260 % 32 == 4)
//   xt / ostg [row][step], row stride XS=68 floats
// Step math verbatim from rounds 4/5 (bit-exact vs numpy):
//   c1 = (p^s1m) >= L1f ; c2 = ((p^f2m) - a3f) >= a4f
//   p  = c2 ? (c1 ? V11 : V01) : (c1 ? L1 : p)

#define C 64
#define NCH 32  // T / C
#define TS 65   // tile row stride (float4)
#define XS 68   // xt/ostg row stride (floats)

#define WG_BARRIER() asm volatile("s_waitcnt lgkmcnt(0)\ns_barrier" ::: "memory")

__global__ __launch_bounds__(192) void pc_scan(
    const float* __restrict__ x, const float* __restrict__ p0,
    const float4* __restrict__ lstm4, float* __restrict__ out,
    int B, int T) {
#pragma clang fp contract(off)
  __shared__ float4 tileA[2][8 * TS];  // (s1m, L1f, f2m, a3f)
  __shared__ float4 tileB[2][8 * TS];  // (a4f, V11, V01, L1)
  __shared__ float xt[8 * XS];         // x exchange [row][step]
  __shared__ float ostg[2][8 * XS];    // outputs [row][step]

  const int tid = threadIdx.x;
  const int b0 = blockIdx.x * 8;
  const float4* x4 = reinterpret_cast<const float4*>(x);
  float4* out4 = reinterpret_cast<float4*>(out);

  const int q = tid - 64;
  const int pj = (q >> 4) & 7;   // row 0..7
  const int pk = q & 15;         // step phase 0..15

  float4 L00, L01, L02, L03;  // lstm set 0 (steps pk+16I)
  float4 L10, L11, L12, L13;  // lstm set 1
  float4 X0, X1;              // x set 0/1 (steps 4pk..4pk+3)

#define ISSUE(S, CH)                                                    \
  if (tid >= 64) {                                                      \
    size_t rb = (size_t)(b0 + pj) * T + (size_t)(CH) * C;               \
    const float4* lp = lstm4 + rb + pk;                                 \
    L##S##0 = lp[0];  L##S##1 = lp[16];                                 \
    L##S##2 = lp[32]; L##S##3 = lp[48];                                 \
    X##S = x4[(rb >> 2) + pk];                                          \
  }

#define STAGE_ELT(LV, SS, BUF)                                          \
  {                                                                     \
    float4 wv = LV; /* (m_lo, m_up, c_lo, c_up) */                      \
    float xv = xt[pj * XS + (SS)];                                      \
    float a1 = wv.x * xv, a2 = wv.x * wv.z;                             \
    float L1v = a1 + a2;                                                \
    unsigned s1m = __float_as_uint(wv.x) & 0x80000000u;                 \
    float L1f = __uint_as_float(__float_as_uint(L1v) ^ s1m);            \
    float a3 = wv.y * xv, a4 = wv.y * wv.w;                             \
    unsigned f2m = (__float_as_uint(wv.y) & 0x80000000u) ^ 0x80000000u; \
    float a3f = __uint_as_float(__float_as_uint(a3) ^ f2m);             \
    float a4f = __uint_as_float(__float_as_uint(a4) ^ f2m);             \
    float V01 = a3 + a4;                                                \
    float V11 = (L1v + a3) + a4;                                        \
    tileA[BUF][pj * TS + (SS)] =                                        \
        make_float4(__uint_as_float(s1m), L1f, __uint_as_float(f2m), a3f); \
    tileB[BUF][pj * TS + (SS)] = make_float4(a4f, V11, V01, L1v);       \
  }

#define STAGE(S, BUF)                                                   \
  if (tid >= 64) {                                                      \
    *(float4*)&xt[pj * XS + 4 * pk] = X##S;                             \
    STAGE_ELT(L##S##0, pk,      BUF)                                    \
    STAGE_ELT(L##S##1, pk + 16, BUF)                                    \
    STAGE_ELT(L##S##2, pk + 32, BUF)                                    \
    STAGE_ELT(L##S##3, pk + 48, BUF)                                    \
  }

#define FLUSH(CP, OB)                                                   \
  if (tid >= 64) {                                                      \
    float4 v = *(const float4*)&ostg[OB][pj * XS + 4 * pk];             \
    out4[(((size_t)(b0 + pj) * T + (size_t)(CP) * C) >> 2) + pk] = v;   \
  }

  // consumer step on ring slot I (data = step 8g+I); reload 8 steps ahead
#define RSTEP(I, OVC)                                                   \
  {                                                                     \
    float4 A = rA##I;                                                   \
    float4 Bv = rB##I;                                                  \
    if (g < 7) {                                                        \
      rA##I = ta[8 * g + 8 + I];                                        \
      rB##I = tb[8 * g + 8 + I];                                        \
    }                                                                   \
    unsigned pu = __float_as_uint(p);                                   \
    float pf = __uint_as_float(pu ^ __float_as_uint(A.x));              \
    bool c1 = pf >= A.y;                                                \
    float pp = __uint_as_float(pu ^ __float_as_uint(A.z));              \
    float qv = pp - A.w;                                                \
    bool c2 = qv >= Bv.x;                                               \
    float i1 = c1 ? Bv.y : Bv.z;                                        \
    float i2 = c1 ? Bv.w : p;                                           \
    p = c2 ? i1 : i2;                                                   \
    OVC = p;                                                            \
  }

#define SCAN(BUF, OB)                                                   \
  if (tid < 8) {                                                        \
    const float4* ta = &tileA[BUF][tid * TS];                           \
    const float4* tb = &tileB[BUF][tid * TS];                           \
    float* orow = &ostg[OB][tid * XS];                                  \
    float4 rA0 = ta[0], rA1 = ta[1], rA2 = ta[2], rA3 = ta[3];          \
    float4 rA4 = ta[4], rA5 = ta[5], rA6 = ta[6], rA7 = ta[7];          \
    float4 rB0 = tb[0], rB1 = tb[1], rB2 = tb[2], rB3 = tb[3];          \
    float4 rB4 = tb[4], rB5 = tb[5], rB6 = tb[6], rB7 = tb[7];          \
    _Pragma("unroll") for (int g = 0; g < 8; ++g) {                     \
      float4 ov0, ov1;                                                  \
      RSTEP(0, ov0.x) RSTEP(1, ov0.y) RSTEP(2, ov0.z) RSTEP(3, ov0.w)   \
      RSTEP(4, ov1.x) RSTEP(5, ov1.y) RSTEP(6, ov1.z) RSTEP(7, ov1.w)   \
      *(float4*)&orow[8 * g] = ov0;                                     \
      *(float4*)&orow[8 * g + 4] = ov1;                                 \
    }                                                                   \
  }

  float p = (tid < 8) ? p0[b0 + tid] : 0.0f;

  // prologue: chunk0 -> buf0; chunk1 loads in flight (set1)
  ISSUE(0, 0)
  STAGE(0, 0)
  ISSUE(1, 1)
  WG_BARRIER();

  for (int c = 0; c < NCH; c += 2) {
    // even phase: scan chunk c (buf0); issue c+2 (set0); stage c+1 (set1->buf1);
    // flush chunk c-1 (ostg1)
    if (c + 2 < NCH) ISSUE(0, c + 2)
    STAGE(1, 1)
    if (c >= 1) FLUSH(c - 1, 1)
    SCAN(0, 0)
    WG_BARRIER();

    // odd phase: scan chunk c+1 (buf1); issue c+3 (set1); stage c+2 (set0->buf0);
    // flush chunk c (ostg0)
    if (c + 3 < NCH) ISSUE(1, c + 3)
    if (c + 2 < NCH) STAGE(0, 0)
    FLUSH(c, 0)
    SCAN(1, 1)
    WG_BARRIER();
  }
  FLUSH(NCH - 1, 1)  // last (odd) chunk's outputs
}

extern "C" void kernel_launch(void* const* d_in, const int* in_sizes, int n_in,
                              void* d_out, int out_size, void* d_ws, size_t ws_size,
                              hipStream_t stream) {
  const float* x = (const float*)d_in[0];        // (B, T, 1) fp32
  const float* op = (const float*)d_in[1];       // (B, 1, 1) fp32
  const float4* lstm = (const float4*)d_in[2];   // (B, T, 4) fp32
  int B = in_sizes[1];      // 4096
  int T = in_sizes[0] / B;  // 2048
  hipLaunchKernelGGL(pc_scan, dim3(B / 8), dim3(192), 0, stream,
                     x, op, lstm, (float*)d_out, B, T);
}

// Round 7
// 230.575 us; speedup vs baseline: 4.9334x; 1.0286x over previous
//
#include <hip/hip_runtime.h>

// R7: barrier-free producer/consumer backlash scan with LDS spin-flags.
// Grid: 256 blocks x 192 threads (3 waves), 1 block/CU. Block owns 16 rows.
// Wave 0 lanes 0..15: consumer (recurrence, 8-deep LDS->reg ring).
// Waves 1-2 (tid 64..191): producers; q=tid-64: pj=(q>>3)&15 row, pk=q&7.
// Chunks of C=64 steps. Tile ring NTB=3 (producers <=3 ahead), output ring NOB=4.
// Sync: per-wave in-order DS completion => a volatile LDS flag written after
// payload DS ops implies payload visibility. No __syncthreads after init.
// Step math verbatim from R4-R6 (bit-exact vs numpy):
//   c1 = (p^s1m) >= L1f ; c2 = ((p^f2m) - a3f) >= a4f
//   p  = c2 ? (c1 ? V11 : V01) : (c1 ? L1 : p)

#define C 64
#define NCH 32  // T / C
#define NTB 3   // tile buffers
#define NOB 4   // output buffers
#define TS 65   // tile row stride (float4): word stride 260 % 32 == 4 -> 2-way max
#define XS 68   // xt/ostg row stride (floats)

#define CFENCE() asm volatile("" ::: "memory")

__global__ __launch_bounds__(192) void pc_scan(
    const float* __restrict__ x, const float* __restrict__ p0,
    const float4* __restrict__ lstm4, float* __restrict__ out,
    int B, int T) {
#pragma clang fp contract(off)
  __shared__ float4 tileA[NTB][16 * TS];  // (s1m, L1f, f2m, a3f)
  __shared__ float4 tileB[NTB][16 * TS];  // (a4f, V11, V01, L1)
  __shared__ float xt[16 * XS];           // x exchange [row][step] (per-wave reuse safe)
  __shared__ float ostg[NOB][16 * XS];    // outputs [row][step]
  __shared__ int stagedw[2][NCH];         // per-producer-wave stage flags
  __shared__ int scanned;                 // chunks fully scanned (consumer)

  const int tid = threadIdx.x;
  const int b0 = blockIdx.x * 16;
  const float4* x4 = reinterpret_cast<const float4*>(x);
  float4* out4 = reinterpret_cast<float4*>(out);

  // init flags
  for (int i = tid; i < 2 * NCH; i += 192) ((int*)stagedw)[i] = 0;
  if (tid == 0) scanned = 0;
  __syncthreads();

  if (tid >= 64) {
    // ======================= PRODUCERS =======================
    const int q = tid - 64;
    const int pj = (q >> 3) & 15;  // row
    const int pk = q & 7;          // step phase
    const int w = (tid >> 6) - 1;  // producer wave id 0/1
    const bool lead = (q & 63) == 0;

    float4 L00, L01, L02, L03, L04, L05, L06, L07;
    float4 L10, L11, L12, L13, L14, L15, L16, L17;
    float4 X00, X01, X10, X11;

#define ISSUE(S, CH)                                                    \
  {                                                                     \
    size_t rb = (size_t)(b0 + pj) * T + (size_t)(CH) * C;               \
    const float4* lp = lstm4 + rb + pk;                                 \
    L##S##0 = lp[0];  L##S##1 = lp[8];  L##S##2 = lp[16];               \
    L##S##3 = lp[24]; L##S##4 = lp[32]; L##S##5 = lp[40];               \
    L##S##6 = lp[48]; L##S##7 = lp[56];                                 \
    X##S##0 = x4[(rb >> 2) + 2 * pk];                                   \
    X##S##1 = x4[(rb >> 2) + 2 * pk + 1];                               \
  }

#define STAGE_ELT(LV, SS, BUF)                                          \
  {                                                                     \
    float4 wv = LV; /* (m_lo, m_up, c_lo, c_up) */                      \
    float xv = xt[pj * XS + (SS)];                                      \
    float a1 = wv.x * xv, a2 = wv.x * wv.z;                             \
    float L1v = a1 + a2;                                                \
    unsigned s1m = __float_as_uint(wv.x) & 0x80000000u;                 \
    float L1f = __uint_as_float(__float_as_uint(L1v) ^ s1m);            \
    float a3 = wv.y * xv, a4 = wv.y * wv.w;                             \
    unsigned f2m = (__float_as_uint(wv.y) & 0x80000000u) ^ 0x80000000u; \
    float a3f = __uint_as_float(__float_as_uint(a3) ^ f2m);             \
    float a4f = __uint_as_float(__float_as_uint(a4) ^ f2m);             \
    float V01 = a3 + a4;                                                \
    float V11 = (L1v + a3) + a4;                                        \
    tileA[BUF][pj * TS + (SS)] =                                        \
        make_float4(__uint_as_float(s1m), L1f, __uint_as_float(f2m), a3f); \
    tileB[BUF][pj * TS + (SS)] = make_float4(a4f, V11, V01, L1v);       \
  }

#define STAGE(S, BUF)                                                   \
  {                                                                     \
    *(float4*)&xt[pj * XS + 8 * pk] = X##S##0;                          \
    *(float4*)&xt[pj * XS + 8 * pk + 4] = X##S##1;                      \
    STAGE_ELT(L##S##0, pk,      BUF)                                    \
    STAGE_ELT(L##S##1, pk + 8,  BUF)                                    \
    STAGE_ELT(L##S##2, pk + 16, BUF)                                    \
    STAGE_ELT(L##S##3, pk + 24, BUF)                                    \
    STAGE_ELT(L##S##4, pk + 32, BUF)                                    \
    STAGE_ELT(L##S##5, pk + 40, BUF)                                    \
    STAGE_ELT(L##S##6, pk + 48, BUF)                                    \
    STAGE_ELT(L##S##7, pk + 56, BUF)                                    \
  }

#define FLUSH(CP, OB)                                                   \
  {                                                                     \
    float4 v0 = *(const float4*)&ostg[OB][pj * XS + 8 * pk];            \
    float4 v1 = *(const float4*)&ostg[OB][pj * XS + 8 * pk + 4];        \
    size_t ob = ((size_t)(b0 + pj) * T + (size_t)(CP) * C) >> 2;        \
    out4[ob + 2 * pk] = v0;                                             \
    out4[ob + 2 * pk + 1] = v1;                                         \
  }

#define PWAIT(TGT)                                                      \
  while (*(volatile int*)&scanned < (TGT)) __builtin_amdgcn_s_sleep(1); \
  CFENCE();

    ISSUE(0, 0)
    ISSUE(1, 1)

    for (int k = 0; k < NCH; k += 2) {
      // chunk k (set 0)
      PWAIT(k - 2)               // slot k%3 free (chunk k-3 scanned)
      STAGE(0, k % NTB)
      CFENCE();
      if (lead) *(volatile int*)&stagedw[w][k] = 1;
      if (k + 2 < NCH) ISSUE(0, k + 2)
      if (k >= 3) FLUSH(k - 3, (k - 3) % NOB)
      // chunk k+1 (set 1)
      PWAIT(k - 1)
      STAGE(1, (k + 1) % NTB)
      CFENCE();
      if (lead) *(volatile int*)&stagedw[w][k + 1] = 1;
      if (k + 3 < NCH) ISSUE(1, k + 3)
      if (k >= 2) FLUSH(k - 2, (k - 2) % NOB)
    }
    // tail: chunks NCH-3..NCH-1
    for (int j = NCH - 3; j < NCH; ++j) {
      PWAIT(j + 1)
      FLUSH(j, j % NOB)
    }
  } else {
    // ======================= CONSUMER (wave 0) =======================
    float p = (tid < 16) ? p0[b0 + tid] : 0.0f;

#define RSTEP(I, OVC)                                                   \
  {                                                                     \
    float4 A = rA##I;                                                   \
    float4 Bv = rB##I;                                                  \
    if (g < 7) {                                                        \
      rA##I = ta[8 * g + 8 + I];                                        \
      rB##I = tb[8 * g + 8 + I];                                        \
    }                                                                   \
    unsigned pu = __float_as_uint(p);                                   \
    float pf = __uint_as_float(pu ^ __float_as_uint(A.x));              \
    bool c1 = pf >= A.y;                                                \
    float pp = __uint_as_float(pu ^ __float_as_uint(A.z));              \
    float qv = pp - A.w;                                                \
    bool c2 = qv >= Bv.x;                                               \
    float i1 = c1 ? Bv.y : Bv.z;                                        \
    float i2 = c1 ? Bv.w : p;                                           \
    p = c2 ? i1 : i2;                                                   \
    OVC = p;                                                            \
  }

    for (int c = 0; c < NCH; ++c) {
      // wait until both producer waves staged chunk c
      for (;;) {
        int a = *(volatile int*)&stagedw[0][c];
        int b = *(volatile int*)&stagedw[1][c];
        if (a + b == 2) break;
        __builtin_amdgcn_s_sleep(1);
      }
      CFENCE();
      if (tid < 16) {
        const float4* ta = &tileA[c % NTB][tid * TS];
        const float4* tb = &tileB[c % NTB][tid * TS];
        float* orow = &ostg[c % NOB][tid * XS];
        float4 rA0 = ta[0], rA1 = ta[1], rA2 = ta[2], rA3 = ta[3];
        float4 rA4 = ta[4], rA5 = ta[5], rA6 = ta[6], rA7 = ta[7];
        float4 rB0 = tb[0], rB1 = tb[1], rB2 = tb[2], rB3 = tb[3];
        float4 rB4 = tb[4], rB5 = tb[5], rB6 = tb[6], rB7 = tb[7];
#pragma unroll
        for (int g = 0; g < 8; ++g) {
          float4 ov0, ov1;
          RSTEP(0, ov0.x) RSTEP(1, ov0.y) RSTEP(2, ov0.z) RSTEP(3, ov0.w)
          RSTEP(4, ov1.x) RSTEP(5, ov1.y) RSTEP(6, ov1.z) RSTEP(7, ov1.w)
          *(float4*)&orow[8 * g] = ov0;
          *(float4*)&orow[8 * g + 4] = ov1;
        }
      }
      CFENCE();
      // flag issued after scan's DS ops -> in-order completion guarantees
      // tile reads + ostg writes are visible before producers see it
      if (tid == 0) *(volatile int*)&scanned = c + 1;
    }
  }
}

extern "C" void kernel_launch(void* const* d_in, const int* in_sizes, int n_in,
                              void* d_out, int out_size, void* d_ws, size_t ws_size,
                              hipStream_t stream) {
  const float* x = (const float*)d_in[0];        // (B, T, 1) fp32
  const float* op = (const float*)d_in[1];       // (B, 1, 1) fp32
  const float4* lstm = (const float4*)d_in[2];   // (B, T, 4) fp32
  int B = in_sizes[1];      // 4096
  int T = in_sizes[0] / B;  // 2048
  hipLaunchKernelGGL(pc_scan, dim3(B / 16), dim3(192), 0, stream,
                     x, op, lstm, (float*)d_out, B, T);
}